// Round 4
// baseline (195.043 us; speedup 1.0000x reference)
//
#include <hip/hip_runtime.h>

#define BATCH 16384
#define LAYERS 63
#define BM 128
#define XS 72              // Hs row stride in bf16: 144 B
#define TILES 8            // batch tiles per persistent block
#define BLOB_BYTES 21504   // W12 16384 | W3 4096 | b1 256 | b2 256 | b3 128 | pad

typedef float f4 __attribute__((ext_vector_type(4)));
typedef short s8 __attribute__((ext_vector_type(8)));          // 8 x bf16
typedef unsigned int u4 __attribute__((ext_vector_type(4)));   // same 16 B as s8

__device__ __forceinline__ float fast_tanh(float v) {
    float e = __expf(2.f * v);
    return 1.f - 2.f / (e + 1.f);
}
__device__ __forceinline__ float softplus_f(float v) {
    return fmaxf(v, 0.f) + __logf(1.f + __expf(-fabsf(v)));
}
__device__ __forceinline__ unsigned short f2bf(float f) {   // RNE fp32->bf16
    unsigned int u = __float_as_uint(f);
    u += 0x7fffu + ((u >> 16) & 1u);
    return (unsigned short)(u >> 16);
}
__device__ __forceinline__ unsigned long long pack4(float a, float b, float c, float d) {
    return (unsigned long long)((unsigned)f2bf(a) | ((unsigned)f2bf(b) << 16))
         | ((unsigned long long)((unsigned)f2bf(c) | ((unsigned)f2bf(d) << 16)) << 32);
}

// RQS spline for one (b,d). Verified vs reference in rounds 1-3.
__device__ __forceinline__ void rqs_eval(const float* p, float xv, float& zout, float& ldout) {
    const bool inside = (xv >= -3.f) && (xv <= 3.f);
    const float xi = fminf(fmaxf(xv, -3.f), 3.f);

    float wa[8], ha[8];
    {   // widths = softmax(6*softmax(p[0:8])) then affine (reference double-softmax)
        float m = p[0];
        #pragma unroll
        for (int i = 1; i < 8; i++) m = fmaxf(m, p[i]);
        float s = 0.f;
        #pragma unroll
        for (int i = 0; i < 8; i++) { wa[i] = __expf(p[i] - m); s += wa[i]; }
        float inv = 6.f / s;
        #pragma unroll
        for (int i = 0; i < 8; i++) wa[i] *= inv;
        m = wa[0];
        #pragma unroll
        for (int i = 1; i < 8; i++) m = fmaxf(m, wa[i]);
        s = 0.f;
        #pragma unroll
        for (int i = 0; i < 8; i++) { wa[i] = __expf(wa[i] - m); s += wa[i]; }
        inv = 0.992f / s;
        #pragma unroll
        for (int i = 0; i < 8; i++) wa[i] = 1e-3f + wa[i] * inv;
    }
    {
        float m = p[8];
        #pragma unroll
        for (int i = 1; i < 8; i++) m = fmaxf(m, p[8 + i]);
        float s = 0.f;
        #pragma unroll
        for (int i = 0; i < 8; i++) { ha[i] = __expf(p[8 + i] - m); s += ha[i]; }
        float inv = 6.f / s;
        #pragma unroll
        for (int i = 0; i < 8; i++) ha[i] *= inv;
        m = ha[0];
        #pragma unroll
        for (int i = 1; i < 8; i++) m = fmaxf(m, ha[i]);
        s = 0.f;
        #pragma unroll
        for (int i = 0; i < 8; i++) { ha[i] = __expf(ha[i] - m); s += ha[i]; }
        inv = 0.992f / s;
        #pragma unroll
        for (int i = 0; i < 8; i++) ha[i] = 1e-3f + ha[i] * inv;
    }

    float cw[9], ch[9];
    cw[0] = -3.f; ch[0] = -3.f;
    {
        float cs = 0.f, hs = 0.f;
        #pragma unroll
        for (int k = 1; k < 8; k++) {
            cs += wa[k - 1]; cw[k] = 6.f * cs - 3.f;
            hs += ha[k - 1]; ch[k] = 6.f * hs - 3.f;
        }
    }
    cw[8] = 3.f; ch[8] = 3.f;

    float dv[9];
    dv[0] = 1.0f; dv[8] = 1.0f;   // boundary: 1e-3 + softplus(log(exp(1-1e-3)-1)) == 1.0
    #pragma unroll
    for (int k = 1; k < 8; k++) dv[k] = 1e-3f + softplus_f(softplus_f(p[15 + k]));

    int cnt = 0;
    #pragma unroll
    for (int k = 0; k < 8; k++) cnt += (xi >= cw[k]) ? 1 : 0;
    cnt += (xi >= 3.000001f) ? 1 : 0;
    const int bin = min(max(cnt - 1, 0), 7);

    float in_cw = 0.f, in_w = 1.f, in_ch = 0.f, in_h = 1.f, dk = 1.f, dk1 = 1.f;
    #pragma unroll
    for (int k = 0; k < 8; k++)
        if (k == bin) {
            in_cw = cw[k]; in_w = cw[k + 1] - cw[k];
            in_ch = ch[k]; in_h = ch[k + 1] - ch[k];
            dk = dv[k]; dk1 = dv[k + 1];
        }

    const float delta = in_h / in_w;
    const float th  = (xi - in_cw) / in_w;
    const float omt = 1.f - th;
    const float t1  = th * omt;
    const float th2 = th * th;
    const float numer = in_h * (delta * th2 + dk * t1);
    const float denom = delta + (dk + dk1 - 2.f * delta) * t1;
    const float outv  = in_ch + numer / denom;
    const float dnum  = delta * delta * (dk1 * th2 + 2.f * delta * t1 + dk * omt * omt);
    const float ldv = __logf(dnum) - 2.f * __logf(denom);

    zout  = inside ? outv : xv;
    ldout = inside ? ldv : 0.f;
}

// Prep: x -> bf16; weights -> per-layer bf16 blob in LDS-image order with XOR-8
// 16B-block swizzle. Biases stay f32, appended.
__global__ __launch_bounds__(256) void prep_kernel(
    const float* __restrict__ x,
    const float* __restrict__ W1, const float* __restrict__ W2, const float* __restrict__ W3,
    const float* __restrict__ b1, const float* __restrict__ b2, const float* __restrict__ b3,
    unsigned short* __restrict__ x_bf, unsigned char* __restrict__ blobG)
{
    const int tid = threadIdx.x;
    if (blockIdx.x < 1024) {                    // x convert: 262144 quads
        size_t idx = (size_t)blockIdx.x * 256 + tid;
        f4 v = *(const f4*)&x[idx * 4];
        *(unsigned long long*)&x_bf[idx * 4] = pack4(v[0], v[1], v[2], v[3]);
        return;
    }
    const int l = blockIdx.x - 1024;
    unsigned char* gb = blobG + (size_t)l * BLOB_BYTES;
    for (int e = tid; e < 1024; e += 256) {     // W1|W2: (m, row r, block j)
        int m = e >> 9, r = (e >> 3) & 63, j = e & 7;
        const float* src = (m ? W2 : W1) + (size_t)l * 4096 + r * 64 + j * 8;
        unsigned long long lo = pack4(src[0], src[1], src[2], src[3]);
        unsigned long long hi = pack4(src[4], src[5], src[6], src[7]);
        unsigned long long* dst = (unsigned long long*)(gb + m * 8192 + r * 128 + ((j ^ (r & 7)) << 4));
        dst[0] = lo; dst[1] = hi;
    }
    if (tid < 256) {                            // W3 padded to 32 rows
        int r = tid >> 3, j = tid & 7;
        unsigned long long lo = 0ull, hi = 0ull;
        if (r < 23) {
            const float* src = W3 + (size_t)l * 1472 + r * 64 + j * 8;
            lo = pack4(src[0], src[1], src[2], src[3]);
            hi = pack4(src[4], src[5], src[6], src[7]);
        }
        unsigned long long* dst = (unsigned long long*)(gb + 16384 + r * 128 + ((j ^ (r & 7)) << 4));
        dst[0] = lo; dst[1] = hi;
    }
    if (tid < 64)        *(float*)(gb + 20480 + tid * 4)         = b1[l * 64 + tid];
    else if (tid < 128)  *(float*)(gb + 20736 + (tid - 64) * 4)  = b2[l * 64 + tid - 64];
    else if (tid < 160)  *(float*)(gb + 20992 + (tid - 128) * 4) = (tid - 128 < 23) ? b3[l * 23 + tid - 128] : 0.f;
    else                 { int e = tid - 160; if (e < 96) *(float*)(gb + 21120 + e * 4) = 0.f; }
}

// Persistent per-layer block: blob DMA'd once, then TILES batch-tiles of 128
// rows. A-frags prefetched one tile ahead. Ps overlaid on wave-own Hs rows
// (h2 dead after GEMM3, wave-private -> no extra LDS, no extra barrier).
// z written directly in final [b][d] layout; logdet transposed for the reduce.
__global__ __launch_bounds__(256, 4) void mlp_rqs_kernel(
    const float* __restrict__ x, const unsigned short* __restrict__ x_bf,
    const unsigned char* __restrict__ blobG,
    float* __restrict__ z, float* __restrict__ ldT)
{
    const int l = blockIdx.y, keff = l + 1;
    const int tid = threadIdx.x;
    const int ln = tid & 63, wv = tid >> 6;
    const int c = ln & 15, q = ln >> 4;
    const int mbase = wv * 32;
    const int c7 = c & 7;
    const int bbase = blockIdx.x * (TILES * BM);

    __shared__ __align__(16) unsigned char blob[BLOB_BYTES];
    __shared__ __align__(16) unsigned short Hs[BM * XS];

    unsigned short* W12s = (unsigned short*)blob;
    unsigned short* W3s  = (unsigned short*)(blob + 16384);
    const float* b1s = (const float*)(blob + 20480);
    const float* b2s = (const float*)(blob + 20736);
    const float* b3s = (const float*)(blob + 20992);
    float* PsF = (float*)Hs;   // Ps row r = 24 floats at word r*36 (row stride 144 B)

    // ---- async DMA: whole layer blob, once per block ----
    {
        const unsigned char* g = blobG + (size_t)l * BLOB_BYTES + ln * 16;
        for (int t = wv; t < 21; t += 4)
            __builtin_amdgcn_global_load_lds(
                (const __attribute__((address_space(1))) void*)(g + t * 1024),
                (__attribute__((address_space(3))) void*)(blob + t * 1024), 16, 0, 0);
    }

    // ---- tril mask for boundary K chunk (constant per block) ----
    const int ks1 = (keff + 31) >> 5;     // 1 or 2
    unsigned mk[4];
    {
        const int n = keff - ((ks1 - 1) * 32 + q * 8);
        #pragma unroll
        for (int i = 0; i < 4; i++) {
            int m = n - 2 * i;
            mk[i] = (m >= 2) ? 0xFFFFFFFFu : ((m == 1) ? 0xFFFFu : 0u);
        }
    }

    // ---- preload tile 0 A-frags ----
    u4 cur0, cur1, cur2{}, cur3{};
    {
        const unsigned short* xr = x_bf + (size_t)(bbase + mbase + c) * 64 + q * 8;
        cur0 = *(const u4*)xr;  cur1 = *(const u4*)(xr + 1024);
        if (ks1 == 2) { cur2 = *(const u4*)(xr + 32); cur3 = *(const u4*)(xr + 1024 + 32); }
    }
    __syncthreads();   // blob resident

    for (int t = 0; t < TILES; ++t) {
        const int b0 = bbase + t * BM;

        // masked A copies (cur regs freed for prefetch)
        u4 A0u = cur0, A1u = cur1, A2u = cur2, A3u = cur3;
        if (ks1 == 2) {
            #pragma unroll
            for (int i = 0; i < 4; i++) { A2u[i] &= mk[i]; A3u[i] &= mk[i]; }
        } else {
            #pragma unroll
            for (int i = 0; i < 4; i++) { A0u[i] &= mk[i]; A1u[i] &= mk[i]; }
        }
        // prefetch next tile's A-frags (overlaps GEMM1-3)
        if (t < TILES - 1) {
            const unsigned short* xr = x_bf + (size_t)(b0 + BM + mbase + c) * 64 + q * 8;
            cur0 = *(const u4*)xr;  cur1 = *(const u4*)(xr + 1024);
            if (ks1 == 2) { cur2 = *(const u4*)(xr + 32); cur3 = *(const u4*)(xr + 1024 + 32); }
        }

        // ---- GEMM1: H1 = tanh(X W1^T + b1), K truncated by tril ----
        {
            f4 acc[2][4];
            #pragma unroll
            for (int nt = 0; nt < 4; nt++) {
                float bv = b1s[nt * 16 + c];
                acc[0][nt] = f4{bv, bv, bv, bv};
                acc[1][nt] = f4{bv, bv, bv, bv};
            }
            {
                const int s0 = (q ^ c7) * 8;
                s8 A0 = __builtin_bit_cast(s8, A0u), A1 = __builtin_bit_cast(s8, A1u);
                #pragma unroll
                for (int nt = 0; nt < 4; nt++) {
                    s8 bb = *(const s8*)&W12s[(nt * 16 + c) * 64 + s0];
                    acc[0][nt] = __builtin_amdgcn_mfma_f32_16x16x32_bf16(A0, bb, acc[0][nt], 0, 0, 0);
                    acc[1][nt] = __builtin_amdgcn_mfma_f32_16x16x32_bf16(A1, bb, acc[1][nt], 0, 0, 0);
                }
            }
            if (ks1 == 2) {
                const int s1 = ((4 + q) ^ c7) * 8;
                s8 A0 = __builtin_bit_cast(s8, A2u), A1 = __builtin_bit_cast(s8, A3u);
                #pragma unroll
                for (int nt = 0; nt < 4; nt++) {
                    s8 bb = *(const s8*)&W12s[(nt * 16 + c) * 64 + s1];
                    acc[0][nt] = __builtin_amdgcn_mfma_f32_16x16x32_bf16(A0, bb, acc[0][nt], 0, 0, 0);
                    acc[1][nt] = __builtin_amdgcn_mfma_f32_16x16x32_bf16(A1, bb, acc[1][nt], 0, 0, 0);
                }
            }
            #pragma unroll
            for (int mt = 0; mt < 2; mt++)
                #pragma unroll
                for (int nt = 0; nt < 4; nt++)
                    #pragma unroll
                    for (int r = 0; r < 4; r++)
                        Hs[(mbase + mt * 16 + q * 4 + r) * XS + nt * 16 + c] =
                            f2bf(fast_tanh(acc[mt][nt][r]));
        }

        // ---- GEMM2: H2 = tanh(H1 W2^T + b2), overwrite own rows ----
        {
            f4 acc[2][4];
            #pragma unroll
            for (int nt = 0; nt < 4; nt++) {
                float bv = b2s[nt * 16 + c];
                acc[0][nt] = f4{bv, bv, bv, bv};
                acc[1][nt] = f4{bv, bv, bv, bv};
            }
            #pragma unroll
            for (int ks = 0; ks < 2; ks++) {
                s8 h0 = *(const s8*)&Hs[(mbase + c) * XS + ks * 32 + q * 8];
                s8 h1 = *(const s8*)&Hs[(mbase + 16 + c) * XS + ks * 32 + q * 8];
                const int sb = ((ks * 4 + q) ^ c7) * 8;
                #pragma unroll
                for (int nt = 0; nt < 4; nt++) {
                    s8 bb = *(const s8*)&W12s[4096 + (nt * 16 + c) * 64 + sb];
                    acc[0][nt] = __builtin_amdgcn_mfma_f32_16x16x32_bf16(h0, bb, acc[0][nt], 0, 0, 0);
                    acc[1][nt] = __builtin_amdgcn_mfma_f32_16x16x32_bf16(h1, bb, acc[1][nt], 0, 0, 0);
                }
            }
            #pragma unroll
            for (int mt = 0; mt < 2; mt++)
                #pragma unroll
                for (int nt = 0; nt < 4; nt++)
                    #pragma unroll
                    for (int r = 0; r < 4; r++)
                        Hs[(mbase + mt * 16 + q * 4 + r) * XS + nt * 16 + c] =
                            f2bf(fast_tanh(acc[mt][nt][r]));
        }

        // ---- GEMM3: OUT = H2 W3^T + b3 (23 cols padded to 32) ----
        f4 acc3[2][2];
        #pragma unroll
        for (int nt = 0; nt < 2; nt++) {
            float bv = b3s[nt * 16 + c];
            acc3[0][nt] = f4{bv, bv, bv, bv};
            acc3[1][nt] = f4{bv, bv, bv, bv};
        }
        #pragma unroll
        for (int ks = 0; ks < 2; ks++) {
            s8 h0 = *(const s8*)&Hs[(mbase + c) * XS + ks * 32 + q * 8];
            s8 h1 = *(const s8*)&Hs[(mbase + 16 + c) * XS + ks * 32 + q * 8];
            const int sb = ((ks * 4 + q) ^ c7) * 8;
            #pragma unroll
            for (int nt = 0; nt < 2; nt++) {
                s8 bb = *(const s8*)&W3s[(nt * 16 + c) * 64 + sb];
                acc3[0][nt] = __builtin_amdgcn_mfma_f32_16x16x32_bf16(h0, bb, acc3[0][nt], 0, 0, 0);
                acc3[1][nt] = __builtin_amdgcn_mfma_f32_16x16x32_bf16(h1, bb, acc3[1][nt], 0, 0, 0);
            }
        }

        // ---- Ps overlay: wave-own Hs rows, no barrier needed before writes ----
        #pragma unroll
        for (int mt = 0; mt < 2; mt++)
            #pragma unroll
            for (int nt = 0; nt < 2; nt++) {
                int o = nt * 16 + c;
                if (o < 23) {
                    #pragma unroll
                    for (int r = 0; r < 4; r++)
                        PsF[(mbase + mt * 16 + q * 4 + r) * 36 + o] = acc3[mt][nt][r];
                }
            }
        __syncthreads();   // Ps complete across waves

        // ---- fused RQS: one thread per row; z in final layout ----
        if (tid < BM) {
            float p[23];
            #pragma unroll
            for (int j = 0; j < 23; j++) p[j] = PsF[tid * 36 + j];
            const float xv = x[(size_t)(b0 + tid) * 64 + keff];
            float zv, ldv;
            rqs_eval(p, xv, zv, ldv);
            z[(size_t)(b0 + tid) * 64 + keff]   = zv;
            ldT[(size_t)keff * BATCH + b0 + tid] = ldv;
        }
        __syncthreads();   // Ps reads done -> Hs reusable next tile
    }
}

// Reduce logdet over d, d=0 spline column. 256 blocks x 64 rows.
__global__ __launch_bounds__(256) void reduce_kernel(
    const float* __restrict__ x, const float* __restrict__ init_param,
    const float* __restrict__ ldT, float* __restrict__ z, float* __restrict__ ld_out)
{
    __shared__ float red[256];
    const int b0 = blockIdx.x * 64;
    const int tid = threadIdx.x, qd = tid >> 6, bb = tid & 63;

    float s = 0.f;
    const int dlo = qd * 16 + (qd == 0 ? 1 : 0), dhi = qd * 16 + 16;
    for (int d = dlo; d < dhi; ++d)
        s += ldT[(size_t)d * BATCH + b0 + bb];

    if (qd == 0) {   // d = 0: params are init_param for every row
        float p[23];
        #pragma unroll
        for (int j = 0; j < 23; j++) p[j] = init_param[j];
        const float xv = x[(size_t)(b0 + bb) * 64];
        float zv, lv;
        rqs_eval(p, xv, zv, lv);
        z[(size_t)(b0 + bb) * 64] = zv;
        s += lv;
    }
    red[tid] = s;
    __syncthreads();
    if (qd == 0)
        ld_out[b0 + bb] = red[bb] + red[64 + bb] + red[128 + bb] + red[192 + bb];
}

extern "C" void kernel_launch(void* const* d_in, const int* in_sizes, int n_in,
                              void* d_out, int out_size, void* d_ws, size_t ws_size,
                              hipStream_t stream)
{
    const float* x  = (const float*)d_in[0];
    const float* ip = (const float*)d_in[1];
    const float* W1 = (const float*)d_in[2];
    const float* b1 = (const float*)d_in[3];
    const float* W2 = (const float*)d_in[4];
    const float* b2 = (const float*)d_in[5];
    const float* W3 = (const float*)d_in[6];
    const float* b3 = (const float*)d_in[7];

    float* z  = (float*)d_out;                  // [B][64]
    float* ld = z + (size_t)BATCH * 64;         // [B]

    float* ldT = (float*)d_ws;                                            // [64][B]
    unsigned short* x_bf = (unsigned short*)(ldT + (size_t)64 * BATCH);   // [B][64] bf16
    unsigned char*  blobG = (unsigned char*)(x_bf + (size_t)BATCH * 64);  // 63 * 21504 B

    prep_kernel<<<1024 + LAYERS, 256, 0, stream>>>(x, W1, W2, W3, b1, b2, b3, x_bf, blobG);
    mlp_rqs_kernel<<<dim3(BATCH / (TILES * BM), LAYERS), 256, 0, stream>>>(
        x, x_bf, blobG, z, ldT);
    reduce_kernel<<<BATCH / 64, 256, 0, stream>>>(x, ip, ldT, z, ld);
}

// Round 5
// 178.171 us; speedup vs baseline: 1.0947x; 1.0947x over previous
//
#include <hip/hip_runtime.h>

#define BATCH 16384
#define LAYERS 63
#define BM 128
#define XS 72              // Hs row stride in bf16: 144 B
#define TPB 2              // batch tiles per block
#define BLOB_BYTES 21504   // W12 16384 | W3 4096 | b1 256 | b2 256 | b3 128 | pad

typedef float f4 __attribute__((ext_vector_type(4)));
typedef short s8 __attribute__((ext_vector_type(8)));          // 8 x bf16
typedef unsigned int u4 __attribute__((ext_vector_type(4)));   // same 16 B as s8

__device__ __forceinline__ float fast_tanh(float v) {
    float e = __expf(2.f * v);
    return 1.f - 2.f / (e + 1.f);
}
__device__ __forceinline__ float softplus_f(float v) {
    return fmaxf(v, 0.f) + __logf(1.f + __expf(-fabsf(v)));
}
__device__ __forceinline__ unsigned short f2bf(float f) {   // RNE fp32->bf16
    unsigned int u = __float_as_uint(f);
    u += 0x7fffu + ((u >> 16) & 1u);
    return (unsigned short)(u >> 16);
}
#if __has_builtin(__builtin_amdgcn_cvt_pk_bf16_f32)
__device__ __forceinline__ unsigned pk2(float a, float b) {   // gfx950 packed cvt
    auto r = __builtin_amdgcn_cvt_pk_bf16_f32(a, b);
    return __builtin_bit_cast(unsigned, r);
}
#else
__device__ __forceinline__ unsigned pk2(float a, float b) {
    return (unsigned)f2bf(a) | ((unsigned)f2bf(b) << 16);
}
#endif
__device__ __forceinline__ unsigned long long pack4(float a, float b, float c, float d) {
    return (unsigned long long)pk2(a, b) | ((unsigned long long)pk2(c, d) << 32);
}

// RQS spline for one (b,d). Verified vs reference rounds 1-4. Max-subtraction
// skipped in both softmaxes (inputs bounded: |p|<~20, stage-2 in (0,6) -> no
// overflow; exact-math identical to reference).
__device__ __forceinline__ void rqs_eval(const float* p, float xv, float& zout, float& ldout) {
    const bool inside = (xv >= -3.f) && (xv <= 3.f);
    const float xi = fminf(fmaxf(xv, -3.f), 3.f);

    float wa[8], ha[8];
    {
        float s = 0.f;
        #pragma unroll
        for (int i = 0; i < 8; i++) { wa[i] = __expf(p[i]); s += wa[i]; }
        float inv = 6.f / s;
        #pragma unroll
        for (int i = 0; i < 8; i++) wa[i] *= inv;
        s = 0.f;
        #pragma unroll
        for (int i = 0; i < 8; i++) { wa[i] = __expf(wa[i]); s += wa[i]; }
        inv = 0.992f / s;
        #pragma unroll
        for (int i = 0; i < 8; i++) wa[i] = 1e-3f + wa[i] * inv;
    }
    {
        float s = 0.f;
        #pragma unroll
        for (int i = 0; i < 8; i++) { ha[i] = __expf(p[8 + i]); s += ha[i]; }
        float inv = 6.f / s;
        #pragma unroll
        for (int i = 0; i < 8; i++) ha[i] *= inv;
        s = 0.f;
        #pragma unroll
        for (int i = 0; i < 8; i++) { ha[i] = __expf(ha[i]); s += ha[i]; }
        inv = 0.992f / s;
        #pragma unroll
        for (int i = 0; i < 8; i++) ha[i] = 1e-3f + ha[i] * inv;
    }

    float cw[9], ch[9];
    cw[0] = -3.f; ch[0] = -3.f;
    {
        float cs = 0.f, hs = 0.f;
        #pragma unroll
        for (int k = 1; k < 8; k++) {
            cs += wa[k - 1]; cw[k] = 6.f * cs - 3.f;
            hs += ha[k - 1]; ch[k] = 6.f * hs - 3.f;
        }
    }
    cw[8] = 3.f; ch[8] = 3.f;

    float dv[9];
    dv[0] = 1.0f; dv[8] = 1.0f;   // boundary: 1e-3 + softplus(log(exp(1-1e-3)-1)) == 1.0
    #pragma unroll
    for (int k = 1; k < 8; k++) dv[k] = 1e-3f + softplus_f(softplus_f(p[15 + k]));

    int cnt = 0;
    #pragma unroll
    for (int k = 0; k < 8; k++) cnt += (xi >= cw[k]) ? 1 : 0;
    cnt += (xi >= 3.000001f) ? 1 : 0;
    const int bin = min(max(cnt - 1, 0), 7);

    float in_cw = 0.f, in_w = 1.f, in_ch = 0.f, in_h = 1.f, dk = 1.f, dk1 = 1.f;
    #pragma unroll
    for (int k = 0; k < 8; k++)
        if (k == bin) {
            in_cw = cw[k]; in_w = cw[k + 1] - cw[k];
            in_ch = ch[k]; in_h = ch[k + 1] - ch[k];
            dk = dv[k]; dk1 = dv[k + 1];
        }

    const float delta = in_h / in_w;
    const float th  = (xi - in_cw) / in_w;
    const float omt = 1.f - th;
    const float t1  = th * omt;
    const float th2 = th * th;
    const float numer = in_h * (delta * th2 + dk * t1);
    const float denom = delta + (dk + dk1 - 2.f * delta) * t1;
    const float outv  = in_ch + numer / denom;
    const float dnum  = delta * delta * (dk1 * th2 + 2.f * delta * t1 + dk * omt * omt);
    const float ldv = __logf(dnum) - 2.f * __logf(denom);

    zout  = inside ? outv : xv;
    ldout = inside ? ldv : 0.f;
}

// Prep: x -> bf16; weights -> per-layer swizzled bf16 blob; d=0 column
// (init_param is row-uniform): z[:,0] and logdet seed ld[b] = ld0(b).
__global__ __launch_bounds__(256) void prep_kernel(
    const float* __restrict__ x, const float* __restrict__ init_param,
    const float* __restrict__ W1, const float* __restrict__ W2, const float* __restrict__ W3,
    const float* __restrict__ b1, const float* __restrict__ b2, const float* __restrict__ b3,
    unsigned short* __restrict__ x_bf, unsigned char* __restrict__ blobG,
    float* __restrict__ z, float* __restrict__ ld)
{
    const int tid = threadIdx.x;
    if (blockIdx.x < 1024) {                    // x convert: 262144 quads
        size_t idx = (size_t)blockIdx.x * 256 + tid;
        f4 v = *(const f4*)&x[idx * 4];
        *(unsigned long long*)&x_bf[idx * 4] = pack4(v[0], v[1], v[2], v[3]);
        return;
    }
    if (blockIdx.x >= 1024 + LAYERS) {          // d = 0 spline + ld seed
        const int row = (blockIdx.x - 1024 - LAYERS) * 256 + tid;
        float p[23];
        #pragma unroll
        for (int j = 0; j < 23; j++) p[j] = init_param[j];
        float zv, lv;
        rqs_eval(p, x[(size_t)row * 64], zv, lv);
        z[(size_t)row * 64] = zv;
        ld[row] = lv;
        return;
    }
    const int l = blockIdx.x - 1024;
    unsigned char* gb = blobG + (size_t)l * BLOB_BYTES;
    for (int e = tid; e < 1024; e += 256) {     // W1|W2: (m, row r, block j)
        int m = e >> 9, r = (e >> 3) & 63, j = e & 7;
        const float* src = (m ? W2 : W1) + (size_t)l * 4096 + r * 64 + j * 8;
        unsigned long long lo = pack4(src[0], src[1], src[2], src[3]);
        unsigned long long hi = pack4(src[4], src[5], src[6], src[7]);
        unsigned long long* dst = (unsigned long long*)(gb + m * 8192 + r * 128 + ((j ^ (r & 7)) << 4));
        dst[0] = lo; dst[1] = hi;
    }
    if (tid < 256) {                            // W3 padded to 32 rows
        int r = tid >> 3, j = tid & 7;
        unsigned long long lo = 0ull, hi = 0ull;
        if (r < 23) {
            const float* src = W3 + (size_t)l * 1472 + r * 64 + j * 8;
            lo = pack4(src[0], src[1], src[2], src[3]);
            hi = pack4(src[4], src[5], src[6], src[7]);
        }
        unsigned long long* dst = (unsigned long long*)(gb + 16384 + r * 128 + ((j ^ (r & 7)) << 4));
        dst[0] = lo; dst[1] = hi;
    }
    if (tid < 64)        *(float*)(gb + 20480 + tid * 4)         = b1[l * 64 + tid];
    else if (tid < 128)  *(float*)(gb + 20736 + (tid - 64) * 4)  = b2[l * 64 + tid - 64];
    else if (tid < 160)  *(float*)(gb + 20992 + (tid - 128) * 4) = (tid - 128 < 23) ? b3[l * 23 + tid - 128] : 0.f;
    else                 { int e = tid - 160; if (e < 96) *(float*)(gb + 21120 + e * 4) = 0.f; }
}

// One block = one layer x 2 tiles of 128 rows. MFMA operands: A = W (m=hidden),
// B = X/H (n=batch) -> C/D's 4 regs run along HIDDEN, so tanh results are 4
// contiguous bf16: 2 packed cvt + 1 ds_write_b64 per tile (vs 32 ds_write_b16).
// Ps epilogue: ds_write_b128. All global stores at kernel end (no in-loop
// vmcnt drains at barriers). Logdet via unsafeAtomicAdd onto prep's seed.
__global__ __launch_bounds__(256, 4) void mlp_rqs_kernel(
    const float* __restrict__ x, const unsigned short* __restrict__ x_bf,
    const unsigned char* __restrict__ blobG,
    float* __restrict__ z, float* __restrict__ ld)
{
    const int l = blockIdx.y, keff = l + 1;
    const int tid = threadIdx.x;
    const int ln = tid & 63, wv = tid >> 6;
    const int c = ln & 15, q = ln >> 4;
    const int mbase = wv * 32;
    const int c7 = c & 7;
    const int bbase = blockIdx.x * (TPB * BM);

    __shared__ __align__(16) unsigned char blob[BLOB_BYTES];
    __shared__ __align__(16) unsigned short Hs[BM * XS];

    unsigned short* W12s = (unsigned short*)blob;
    unsigned short* W3s  = (unsigned short*)(blob + 16384);
    const float* b1s = (const float*)(blob + 20480);
    const float* b2s = (const float*)(blob + 20736);
    const float* b3s = (const float*)(blob + 20992);
    float* PsF = (float*)Hs;   // Ps row r: 24 floats at word r*36 (row stride 144 B)

    // ---- async DMA: whole layer blob, once per block ----
    {
        const unsigned char* g = blobG + (size_t)l * BLOB_BYTES + ln * 16;
        for (int t = wv; t < 21; t += 4)
            __builtin_amdgcn_global_load_lds(
                (const __attribute__((address_space(1))) void*)(g + t * 1024),
                (__attribute__((address_space(3))) void*)(blob + t * 1024), 16, 0, 0);
    }

    // ---- tril mask for boundary K chunk (constant per block) ----
    const int ks1 = (keff + 31) >> 5;     // 1 or 2
    unsigned mk[4];
    {
        const int n = keff - ((ks1 - 1) * 32 + q * 8);
        #pragma unroll
        for (int i = 0; i < 4; i++) {
            int m = n - 2 * i;
            mk[i] = (m >= 2) ? 0xFFFFFFFFu : ((m == 1) ? 0xFFFFu : 0u);
        }
    }

    // ---- preload tile 0 X B-frags (batch rows mbase+c, mbase+16+c) ----
    u4 cur0, cur1, cur2{}, cur3{};
    {
        const unsigned short* xr = x_bf + (size_t)(bbase + mbase + c) * 64 + q * 8;
        cur0 = *(const u4*)xr;  cur1 = *(const u4*)(xr + 1024);
        if (ks1 == 2) { cur2 = *(const u4*)(xr + 32); cur3 = *(const u4*)(xr + 1024 + 32); }
    }

    // one MLP pass over the resident tile; frags pre-masked
    auto gemms = [&](s8 B0a, s8 B1a, s8 B0b, s8 B1b) {
        // GEMM1: bias along hidden -> f4 from b1s
        f4 acc[4][2];
        #pragma unroll
        for (int mt = 0; mt < 4; mt++) {
            f4 bv = *(const f4*)&b1s[mt * 16 + q * 4];
            acc[mt][0] = bv; acc[mt][1] = bv;
        }
        {
            const int s0 = (q ^ c7) * 8;
            #pragma unroll
            for (int mt = 0; mt < 4; mt++) {
                s8 aw = *(const s8*)&W12s[(mt * 16 + c) * 64 + s0];
                acc[mt][0] = __builtin_amdgcn_mfma_f32_16x16x32_bf16(aw, B0a, acc[mt][0], 0, 0, 0);
                acc[mt][1] = __builtin_amdgcn_mfma_f32_16x16x32_bf16(aw, B1a, acc[mt][1], 0, 0, 0);
            }
        }
        if (ks1 == 2) {
            const int s1 = ((4 + q) ^ c7) * 8;
            #pragma unroll
            for (int mt = 0; mt < 4; mt++) {
                s8 aw = *(const s8*)&W12s[(mt * 16 + c) * 64 + s1];
                acc[mt][0] = __builtin_amdgcn_mfma_f32_16x16x32_bf16(aw, B0b, acc[mt][0], 0, 0, 0);
                acc[mt][1] = __builtin_amdgcn_mfma_f32_16x16x32_bf16(aw, B1b, acc[mt][1], 0, 0, 0);
            }
        }
        #pragma unroll
        for (int mt = 0; mt < 4; mt++)
            #pragma unroll
            for (int nt = 0; nt < 2; nt++) {
                f4 a = acc[mt][nt];
                unsigned long long w = (unsigned long long)pk2(fast_tanh(a[0]), fast_tanh(a[1]))
                    | ((unsigned long long)pk2(fast_tanh(a[2]), fast_tanh(a[3])) << 32);
                *(unsigned long long*)&Hs[(mbase + nt * 16 + c) * XS + mt * 16 + q * 4] = w;
            }

        // GEMM2
        #pragma unroll
        for (int mt = 0; mt < 4; mt++) {
            f4 bv = *(const f4*)&b2s[mt * 16 + q * 4];
            acc[mt][0] = bv; acc[mt][1] = bv;
        }
        #pragma unroll
        for (int ks = 0; ks < 2; ks++) {
            s8 bh0 = *(const s8*)&Hs[(mbase + c) * XS + ks * 32 + q * 8];
            s8 bh1 = *(const s8*)&Hs[(mbase + 16 + c) * XS + ks * 32 + q * 8];
            const int sb = ((ks * 4 + q) ^ c7) * 8;
            #pragma unroll
            for (int mt = 0; mt < 4; mt++) {
                s8 aw = *(const s8*)&W12s[4096 + (mt * 16 + c) * 64 + sb];
                acc[mt][0] = __builtin_amdgcn_mfma_f32_16x16x32_bf16(aw, bh0, acc[mt][0], 0, 0, 0);
                acc[mt][1] = __builtin_amdgcn_mfma_f32_16x16x32_bf16(aw, bh1, acc[mt][1], 0, 0, 0);
            }
        }
        #pragma unroll
        for (int mt = 0; mt < 4; mt++)
            #pragma unroll
            for (int nt = 0; nt < 2; nt++) {
                f4 a = acc[mt][nt];
                unsigned long long w = (unsigned long long)pk2(fast_tanh(a[0]), fast_tanh(a[1]))
                    | ((unsigned long long)pk2(fast_tanh(a[2]), fast_tanh(a[3])) << 32);
                *(unsigned long long*)&Hs[(mbase + nt * 16 + c) * XS + mt * 16 + q * 4] = w;
            }

        // GEMM3: 24 outputs (padded 32) along m
        f4 acc3[2][2];
        #pragma unroll
        for (int mt = 0; mt < 2; mt++) {
            f4 bv = *(const f4*)&b3s[mt * 16 + q * 4];
            acc3[mt][0] = bv; acc3[mt][1] = bv;
        }
        #pragma unroll
        for (int ks = 0; ks < 2; ks++) {
            s8 bh0 = *(const s8*)&Hs[(mbase + c) * XS + ks * 32 + q * 8];
            s8 bh1 = *(const s8*)&Hs[(mbase + 16 + c) * XS + ks * 32 + q * 8];
            const int sb = ((ks * 4 + q) ^ c7) * 8;
            #pragma unroll
            for (int mt = 0; mt < 2; mt++) {
                s8 aw = *(const s8*)&W3s[(mt * 16 + c) * 64 + sb];
                acc3[mt][0] = __builtin_amdgcn_mfma_f32_16x16x32_bf16(aw, bh0, acc3[mt][0], 0, 0, 0);
                acc3[mt][1] = __builtin_amdgcn_mfma_f32_16x16x32_bf16(aw, bh1, acc3[mt][1], 0, 0, 0);
            }
        }
        // Ps overlay on wave-own Hs rows (h2 dead): one b128 per tile
        #pragma unroll
        for (int mt = 0; mt < 2; mt++)
            #pragma unroll
            for (int nt = 0; nt < 2; nt++)
                *(f4*)&PsF[(mbase + nt * 16 + c) * 36 + mt * 16 + q * 4] = acc3[mt][nt];
    };
    auto msk = [&](u4 v) { u4 r;
        #pragma unroll
        for (int i = 0; i < 4; i++) r[i] = v[i] & mk[i];
        return r; };

    // RQS inputs (f32 x — exact passthrough outside the box)
    const float xv0 = x[(size_t)(bbase + (tid & 127)) * 64 + keff];
    const float xv1 = x[(size_t)(bbase + BM + (tid & 127)) * 64 + keff];

    __syncthreads();   // blob resident

    // ---- tile 0 ----
    u4 A0, A1, A2, A3;
    if (ks1 == 2) { A0 = cur0; A1 = cur1; A2 = msk(cur2); A3 = msk(cur3); }
    else          { A0 = msk(cur0); A1 = msk(cur1); A2 = cur2; A3 = cur3; }
    {   // prefetch tile 1 frags
        const unsigned short* xr = x_bf + (size_t)(bbase + BM + mbase + c) * 64 + q * 8;
        cur0 = *(const u4*)xr;  cur1 = *(const u4*)(xr + 1024);
        if (ks1 == 2) { cur2 = *(const u4*)(xr + 32); cur3 = *(const u4*)(xr + 1024 + 32); }
    }
    gemms(__builtin_bit_cast(s8, A0), __builtin_bit_cast(s8, A1),
          __builtin_bit_cast(s8, A2), __builtin_bit_cast(s8, A3));
    __syncthreads();   // Ps(t0) complete
    float p0[23];
    if (tid < BM) {
        #pragma unroll
        for (int j = 0; j < 23; j++) p0[j] = PsF[tid * 36 + j];
    }
    __syncthreads();   // Ps reads done -> Hs reusable

    // ---- tile 1 ----
    if (ks1 == 2) { A0 = cur0; A1 = cur1; A2 = msk(cur2); A3 = msk(cur3); }
    else          { A0 = msk(cur0); A1 = msk(cur1); A2 = cur2; A3 = cur3; }
    gemms(__builtin_bit_cast(s8, A0), __builtin_bit_cast(s8, A1),
          __builtin_bit_cast(s8, A2), __builtin_bit_cast(s8, A3));
    __syncthreads();   // Ps(t1) complete

    if (tid < BM) {
        float p1[23];
        #pragma unroll
        for (int j = 0; j < 23; j++) p1[j] = PsF[tid * 36 + j];
        float zv0, lv0, zv1, lv1;
        rqs_eval(p0, xv0, zv0, lv0);
        rqs_eval(p1, xv1, zv1, lv1);
        z[(size_t)(bbase + tid) * 64 + keff]      = zv0;
        z[(size_t)(bbase + BM + tid) * 64 + keff] = zv1;
        unsafeAtomicAdd(ld + bbase + tid, lv0);
        unsafeAtomicAdd(ld + bbase + BM + tid, lv1);
    }
}

extern "C" void kernel_launch(void* const* d_in, const int* in_sizes, int n_in,
                              void* d_out, int out_size, void* d_ws, size_t ws_size,
                              hipStream_t stream)
{
    const float* x  = (const float*)d_in[0];
    const float* ip = (const float*)d_in[1];
    const float* W1 = (const float*)d_in[2];
    const float* b1 = (const float*)d_in[3];
    const float* W2 = (const float*)d_in[4];
    const float* b2 = (const float*)d_in[5];
    const float* W3 = (const float*)d_in[6];
    const float* b3 = (const float*)d_in[7];

    float* z  = (float*)d_out;                  // [B][64]
    float* ld = z + (size_t)BATCH * 64;         // [B]

    unsigned short* x_bf = (unsigned short*)d_ws;                         // [B][64] bf16
    unsigned char*  blobG = (unsigned char*)(x_bf + (size_t)BATCH * 64);  // 63 * 21504 B

    // grid: 1024 x-convert | 63 blob | 64 d0-spline blocks
    prep_kernel<<<1024 + LAYERS + 64, 256, 0, stream>>>(
        x, ip, W1, W2, W3, b1, b2, b3, x_bf, blobG, z, ld);
    mlp_rqs_kernel<<<dim3(BATCH / (TPB * BM), LAYERS), 256, 0, stream>>>(
        x, x_bf, blobG, z, ld);
}

// Round 6
// 132.739 us; speedup vs baseline: 1.4694x; 1.3423x over previous
//
#include <hip/hip_runtime.h>

#define BATCH 16384
#define LAYERS 63
#define BM 128
#define XS 72              // Hs row stride in bf16: 144 B
#define BLOB_BYTES 21504   // W1 8192 | W2 8192 | W3 4096 | b1 256 | b2 256 | b3 128 | pad
#define LDS_OFF 8192       // W1 goes global->VGPR; LDS images [8192, 21504)
#define LDS_BYTES 13312

typedef float f4 __attribute__((ext_vector_type(4)));
typedef short s8 __attribute__((ext_vector_type(8)));          // 8 x bf16
typedef unsigned int u4 __attribute__((ext_vector_type(4)));   // same 16 B as s8

__device__ __forceinline__ float rcpf(float v) { return __builtin_amdgcn_rcpf(v); }

__device__ __forceinline__ float fast_tanh(float v) {   // 1 exp + 1 rcp + 3 VALU
    float e = __expf(2.f * v);
    return 1.f - 2.f * rcpf(e + 1.f);
}
__device__ __forceinline__ float softplus_f(float v) {
    return fmaxf(v, 0.f) + __logf(1.f + __expf(-fabsf(v)));
}
__device__ __forceinline__ unsigned short f2bf(float f) {   // RNE fp32->bf16
    unsigned int u = __float_as_uint(f);
    u += 0x7fffu + ((u >> 16) & 1u);
    return (unsigned short)(u >> 16);
}
#if __has_builtin(__builtin_amdgcn_cvt_pk_bf16_f32)
__device__ __forceinline__ unsigned pk2(float a, float b) {   // gfx950 packed cvt
    auto r = __builtin_amdgcn_cvt_pk_bf16_f32(a, b);
    return __builtin_bit_cast(unsigned, r);
}
#else
__device__ __forceinline__ unsigned pk2(float a, float b) {
    return (unsigned)f2bf(a) | ((unsigned)f2bf(b) << 16);
}
#endif
__device__ __forceinline__ unsigned long long pack4(float a, float b, float c, float d) {
    return (unsigned long long)pk2(a, b) | ((unsigned long long)pk2(c, d) << 32);
}

// RQS spline for one (b,d). Semantics verified vs reference rounds 1-5.
// Divisions -> v_rcp (1e-7 rel, noise vs bf16 pipeline error). Derivatives:
// select raw param first, then 2 double-softplus (8 transc instead of 28).
__device__ __forceinline__ void rqs_eval(const float* p, float xv, float& zout, float& ldout) {
    const bool inside = (xv >= -3.f) && (xv <= 3.f);
    const float xi = fminf(fmaxf(xv, -3.f), 3.f);

    float wa[8], ha[8];
    {   // widths = affine(softmax(6*softmax(p[0:8]))) — no max-sub (range-safe)
        float s = 0.f;
        #pragma unroll
        for (int i = 0; i < 8; i++) { wa[i] = __expf(p[i]); s += wa[i]; }
        float inv = 6.f * rcpf(s);
        #pragma unroll
        for (int i = 0; i < 8; i++) wa[i] *= inv;
        s = 0.f;
        #pragma unroll
        for (int i = 0; i < 8; i++) { wa[i] = __expf(wa[i]); s += wa[i]; }
        inv = 0.992f * rcpf(s);
        #pragma unroll
        for (int i = 0; i < 8; i++) wa[i] = 1e-3f + wa[i] * inv;
    }
    {
        float s = 0.f;
        #pragma unroll
        for (int i = 0; i < 8; i++) { ha[i] = __expf(p[8 + i]); s += ha[i]; }
        float inv = 6.f * rcpf(s);
        #pragma unroll
        for (int i = 0; i < 8; i++) ha[i] *= inv;
        s = 0.f;
        #pragma unroll
        for (int i = 0; i < 8; i++) { ha[i] = __expf(ha[i]); s += ha[i]; }
        inv = 0.992f * rcpf(s);
        #pragma unroll
        for (int i = 0; i < 8; i++) ha[i] = 1e-3f + ha[i] * inv;
    }

    float cw[9], ch[9];
    cw[0] = -3.f; ch[0] = -3.f;
    {
        float cs = 0.f, hs = 0.f;
        #pragma unroll
        for (int k = 1; k < 8; k++) {
            cs += wa[k - 1]; cw[k] = 6.f * cs - 3.f;
            hs += ha[k - 1]; ch[k] = 6.f * hs - 3.f;
        }
    }
    cw[8] = 3.f; ch[8] = 3.f;

    int cnt = 0;
    #pragma unroll
    for (int k = 0; k < 8; k++) cnt += (xi >= cw[k]) ? 1 : 0;
    cnt += (xi >= 3.000001f) ? 1 : 0;
    const int bin = min(max(cnt - 1, 0), 7);

    float in_cw = 0.f, in_w = 1.f, in_ch = 0.f, in_h = 1.f;
    float pd0 = 0.f, pd1 = 0.f;
    #pragma unroll
    for (int k = 0; k < 8; k++)
        if (k == bin) {
            in_cw = cw[k]; in_w = cw[k + 1] - cw[k];
            in_ch = ch[k]; in_h = ch[k + 1] - ch[k];
            if (k >= 1) pd0 = p[15 + k];
            if (k <= 6) pd1 = p[16 + k];
        }
    // boundary derivs: 1e-3 + softplus(log(exp(1-1e-3)-1)) == 1.0 exactly
    const float dk  = (bin == 0) ? 1.f : 1e-3f + softplus_f(softplus_f(pd0));
    const float dk1 = (bin == 7) ? 1.f : 1e-3f + softplus_f(softplus_f(pd1));

    const float rw    = rcpf(in_w);
    const float delta = in_h * rw;
    const float th    = (xi - in_cw) * rw;
    const float omt = 1.f - th;
    const float t1  = th * omt;
    const float th2 = th * th;
    const float numer = in_h * (delta * th2 + dk * t1);
    const float denom = delta + (dk + dk1 - 2.f * delta) * t1;
    const float outv  = in_ch + numer * rcpf(denom);
    const float dnum  = delta * delta * (dk1 * th2 + 2.f * delta * t1 + dk * omt * omt);
    const float ldv = __logf(dnum) - 2.f * __logf(denom);

    zout  = inside ? outv : xv;
    ldout = inside ? ldv : 0.f;
}

// Prep: x -> bf16; weights -> per-layer swizzled bf16 blob; d=0 column
// (init_param is row-uniform): z[:,0] and logdet seed ld[b].
__global__ __launch_bounds__(256) void prep_kernel(
    const float* __restrict__ x, const float* __restrict__ init_param,
    const float* __restrict__ W1, const float* __restrict__ W2, const float* __restrict__ W3,
    const float* __restrict__ b1, const float* __restrict__ b2, const float* __restrict__ b3,
    unsigned short* __restrict__ x_bf, unsigned char* __restrict__ blobG,
    float* __restrict__ z, float* __restrict__ ld)
{
    const int tid = threadIdx.x;
    if (blockIdx.x < 1024) {                    // x convert: 262144 quads
        size_t idx = (size_t)blockIdx.x * 256 + tid;
        f4 v = *(const f4*)&x[idx * 4];
        *(unsigned long long*)&x_bf[idx * 4] = pack4(v[0], v[1], v[2], v[3]);
        return;
    }
    if (blockIdx.x >= 1024 + LAYERS) {          // d = 0 spline + ld seed
        const int row = (blockIdx.x - 1024 - LAYERS) * 256 + tid;
        float p[23];
        #pragma unroll
        for (int j = 0; j < 23; j++) p[j] = init_param[j];
        float zv, lv;
        rqs_eval(p, x[(size_t)row * 64], zv, lv);
        z[(size_t)row * 64] = zv;
        ld[row] = lv;
        return;
    }
    const int l = blockIdx.x - 1024;
    unsigned char* gb = blobG + (size_t)l * BLOB_BYTES;
    for (int e = tid; e < 1024; e += 256) {     // W1|W2: (m, row r, block j), XOR-8 swizzle
        int m = e >> 9, r = (e >> 3) & 63, j = e & 7;
        const float* src = (m ? W2 : W1) + (size_t)l * 4096 + r * 64 + j * 8;
        unsigned long long lo = pack4(src[0], src[1], src[2], src[3]);
        unsigned long long hi = pack4(src[4], src[5], src[6], src[7]);
        unsigned long long* dst = (unsigned long long*)(gb + m * 8192 + r * 128 + ((j ^ (r & 7)) << 4));
        dst[0] = lo; dst[1] = hi;
    }
    if (tid < 256) {                            // W3 padded to 32 rows
        int r = tid >> 3, j = tid & 7;
        unsigned long long lo = 0ull, hi = 0ull;
        if (r < 23) {
            const float* src = W3 + (size_t)l * 1472 + r * 64 + j * 8;
            lo = pack4(src[0], src[1], src[2], src[3]);
            hi = pack4(src[4], src[5], src[6], src[7]);
        }
        unsigned long long* dst = (unsigned long long*)(gb + 16384 + r * 128 + ((j ^ (r & 7)) << 4));
        dst[0] = lo; dst[1] = hi;
    }
    if (tid < 64)        *(float*)(gb + 20480 + tid * 4)         = b1[l * 64 + tid];
    else if (tid < 128)  *(float*)(gb + 20736 + (tid - 64) * 4)  = b2[l * 64 + tid - 64];
    else if (tid < 160)  *(float*)(gb + 20992 + (tid - 128) * 4) = (tid - 128 < 23) ? b3[l * 23 + tid - 128] : 0.f;
    else                 { int e = tid - 160; if (e < 96) *(float*)(gb + 21120 + e * 4) = 0.f; }
}

// One block = one layer x one 128-row tile (8064 blocks — measured-best regime).
// W1 A-frags live in VGPRs (loaded once from L2-resident blob) -> LDS holds only
// W2/W3/biases (13 KB DMA) + Hs (18 KB) = 31.7 KB -> 5 blocks/CU. A=W, B=X/H:
// C/D regs run along hidden -> packed-cvt + b64 epilogues. 2 barriers total.
__global__ __launch_bounds__(256, 5) void mlp_rqs_kernel(
    const float* __restrict__ x, const unsigned short* __restrict__ x_bf,
    const unsigned char* __restrict__ blobG,
    float* __restrict__ z, float* __restrict__ ld)
{
    const int l = blockIdx.y, keff = l + 1;
    const int b0 = blockIdx.x * BM;
    const int tid = threadIdx.x;
    const int ln = tid & 63, wv = tid >> 6;
    const int c = ln & 15, q = ln >> 4;
    const int mbase = wv * 32;
    const int c7 = c & 7;

    __shared__ __align__(16) unsigned char blob[LDS_BYTES];
    __shared__ __align__(16) unsigned short Hs[BM * XS];

    unsigned short* W2s = (unsigned short*)blob;            // rows 0..63, swizzled
    unsigned short* W3s = (unsigned short*)(blob + 8192);   // rows 0..31, swizzled
    const float* b1s = (const float*)(blob + 12288);
    const float* b2s = (const float*)(blob + 12544);
    const float* b3s = (const float*)(blob + 12800);
    float* PsF = (float*)Hs;   // Ps row r: 24 floats at word r*36 (overlay, h2 dead)

    const unsigned char* gblob = blobG + (size_t)l * BLOB_BYTES;

    // ---- async DMA: W2|W3|biases (13 KB), once per block ----
    for (int t = wv; t < 13; t += 4)
        __builtin_amdgcn_global_load_lds(
            (const __attribute__((address_space(1))) void*)(gblob + LDS_OFF + t * 1024 + ln * 16),
            (__attribute__((address_space(3))) void*)(blob + t * 1024 + ln * 16), 16, 0, 0);

    const int ks1 = (keff + 31) >> 5;     // 1 or 2

    // ---- W1 A-frags -> VGPR (swizzled image, L2-hot) ----
    s8 aw1[2][4];
    #pragma unroll
    for (int mt = 0; mt < 4; mt++)
        aw1[0][mt] = *(const s8*)(gblob + (mt * 16 + c) * 128 + ((q ^ c7) << 4));
    if (ks1 == 2) {
        #pragma unroll
        for (int mt = 0; mt < 4; mt++)
            aw1[1][mt] = *(const s8*)(gblob + (mt * 16 + c) * 128 + (((4 + q) ^ c7) << 4));
    }

    // ---- X B-frags (batch rows mbase+c, mbase+16+c), tril mask in-register ----
    u4 B0u, B1u, B2u{}, B3u{};
    {
        const unsigned short* xr = x_bf + (size_t)(b0 + mbase + c) * 64 + q * 8;
        B0u = *(const u4*)xr;  B1u = *(const u4*)(xr + 1024);
        if (ks1 == 2) { B2u = *(const u4*)(xr + 32); B3u = *(const u4*)(xr + 1024 + 32); }
        const int n = keff - ((ks1 - 1) * 32 + q * 8);   // valid elems in boundary chunk
        unsigned mk[4];
        #pragma unroll
        for (int i = 0; i < 4; i++) {
            int m = n - 2 * i;
            mk[i] = (m >= 2) ? 0xFFFFFFFFu : ((m == 1) ? 0xFFFFu : 0u);
        }
        if (ks1 == 2) {
            #pragma unroll
            for (int i = 0; i < 4; i++) { B2u[i] &= mk[i]; B3u[i] &= mk[i]; }
        } else {
            #pragma unroll
            for (int i = 0; i < 4; i++) { B0u[i] &= mk[i]; B1u[i] &= mk[i]; }
        }
    }
    const float xv = x[(size_t)(b0 + (tid & 127)) * 64 + keff];   // RQS input (f32 exact)

    __syncthreads();   // LDS blob resident

    // ---- GEMM1: H1 = tanh(W1 X^T + b1), K truncated by tril ----
    {
        f4 acc[4][2];
        #pragma unroll
        for (int mt = 0; mt < 4; mt++) {
            f4 bv = *(const f4*)&b1s[mt * 16 + q * 4];
            acc[mt][0] = bv; acc[mt][1] = bv;
        }
        {
            s8 bx0 = __builtin_bit_cast(s8, B0u), bx1 = __builtin_bit_cast(s8, B1u);
            #pragma unroll
            for (int mt = 0; mt < 4; mt++) {
                acc[mt][0] = __builtin_amdgcn_mfma_f32_16x16x32_bf16(aw1[0][mt], bx0, acc[mt][0], 0, 0, 0);
                acc[mt][1] = __builtin_amdgcn_mfma_f32_16x16x32_bf16(aw1[0][mt], bx1, acc[mt][1], 0, 0, 0);
            }
        }
        if (ks1 == 2) {
            s8 bx0 = __builtin_bit_cast(s8, B2u), bx1 = __builtin_bit_cast(s8, B3u);
            #pragma unroll
            for (int mt = 0; mt < 4; mt++) {
                acc[mt][0] = __builtin_amdgcn_mfma_f32_16x16x32_bf16(aw1[1][mt], bx0, acc[mt][0], 0, 0, 0);
                acc[mt][1] = __builtin_amdgcn_mfma_f32_16x16x32_bf16(aw1[1][mt], bx1, acc[mt][1], 0, 0, 0);
            }
        }
        #pragma unroll
        for (int mt = 0; mt < 4; mt++)
            #pragma unroll
            for (int nt = 0; nt < 2; nt++) {
                f4 a = acc[mt][nt];
                unsigned long long w = (unsigned long long)pk2(fast_tanh(a[0]), fast_tanh(a[1]))
                    | ((unsigned long long)pk2(fast_tanh(a[2]), fast_tanh(a[3])) << 32);
                *(unsigned long long*)&Hs[(mbase + nt * 16 + c) * XS + mt * 16 + q * 4] = w;
            }
    }

    // ---- GEMM2: H2 = tanh(W2 H1^T + b2), wave-own rows, no barrier ----
    {
        f4 acc[4][2];
        #pragma unroll
        for (int mt = 0; mt < 4; mt++) {
            f4 bv = *(const f4*)&b2s[mt * 16 + q * 4];
            acc[mt][0] = bv; acc[mt][1] = bv;
        }
        #pragma unroll
        for (int ks = 0; ks < 2; ks++) {
            s8 bh0 = *(const s8*)&Hs[(mbase + c) * XS + ks * 32 + q * 8];
            s8 bh1 = *(const s8*)&Hs[(mbase + 16 + c) * XS + ks * 32 + q * 8];
            const int sb = ((ks * 4 + q) ^ c7) * 8;
            #pragma unroll
            for (int mt = 0; mt < 4; mt++) {
                s8 aw = *(const s8*)&W2s[(mt * 16 + c) * 64 + sb];
                acc[mt][0] = __builtin_amdgcn_mfma_f32_16x16x32_bf16(aw, bh0, acc[mt][0], 0, 0, 0);
                acc[mt][1] = __builtin_amdgcn_mfma_f32_16x16x32_bf16(aw, bh1, acc[mt][1], 0, 0, 0);
            }
        }
        #pragma unroll
        for (int mt = 0; mt < 4; mt++)
            #pragma unroll
            for (int nt = 0; nt < 2; nt++) {
                f4 a = acc[mt][nt];
                unsigned long long w = (unsigned long long)pk2(fast_tanh(a[0]), fast_tanh(a[1]))
                    | ((unsigned long long)pk2(fast_tanh(a[2]), fast_tanh(a[3])) << 32);
                *(unsigned long long*)&Hs[(mbase + nt * 16 + c) * XS + mt * 16 + q * 4] = w;
            }
    }

    // ---- GEMM3: OUT = W3 H2^T + b3 (23 outs padded 32, along m) ----
    {
        f4 acc3[2][2];
        #pragma unroll
        for (int mt = 0; mt < 2; mt++) {
            f4 bv = *(const f4*)&b3s[mt * 16 + q * 4];
            acc3[mt][0] = bv; acc3[mt][1] = bv;
        }
        #pragma unroll
        for (int ks = 0; ks < 2; ks++) {
            s8 bh0 = *(const s8*)&Hs[(mbase + c) * XS + ks * 32 + q * 8];
            s8 bh1 = *(const s8*)&Hs[(mbase + 16 + c) * XS + ks * 32 + q * 8];
            const int sb = ((ks * 4 + q) ^ c7) * 8;
            #pragma unroll
            for (int mt = 0; mt < 2; mt++) {
                s8 aw = *(const s8*)&W3s[(mt * 16 + c) * 64 + sb];
                acc3[mt][0] = __builtin_amdgcn_mfma_f32_16x16x32_bf16(aw, bh0, acc3[mt][0], 0, 0, 0);
                acc3[mt][1] = __builtin_amdgcn_mfma_f32_16x16x32_bf16(aw, bh1, acc3[mt][1], 0, 0, 0);
            }
        }
        // Ps overlay on wave-own Hs rows (h2 dead): b128 writes
        #pragma unroll
        for (int mt = 0; mt < 2; mt++)
            #pragma unroll
            for (int nt = 0; nt < 2; nt++)
                *(f4*)&PsF[(mbase + nt * 16 + c) * 36 + mt * 16 + q * 4] = acc3[mt][nt];
    }
    __syncthreads();   // Ps complete across waves

    // ---- fused RQS: one thread per row; z in final layout; ld atomic ----
    if (tid < BM) {
        float p[23];
        #pragma unroll
        for (int j = 0; j < 23; j++) p[j] = PsF[tid * 36 + j];
        float zv, lv;
        rqs_eval(p, xv, zv, lv);
        z[(size_t)(b0 + tid) * 64 + keff] = zv;
        unsafeAtomicAdd(ld + b0 + tid, lv);
    }
}

extern "C" void kernel_launch(void* const* d_in, const int* in_sizes, int n_in,
                              void* d_out, int out_size, void* d_ws, size_t ws_size,
                              hipStream_t stream)
{
    const float* x  = (const float*)d_in[0];
    const float* ip = (const float*)d_in[1];
    const float* W1 = (const float*)d_in[2];
    const float* b1 = (const float*)d_in[3];
    const float* W2 = (const float*)d_in[4];
    const float* b2 = (const float*)d_in[5];
    const float* W3 = (const float*)d_in[6];
    const float* b3 = (const float*)d_in[7];

    float* z  = (float*)d_out;                  // [B][64]
    float* ld = z + (size_t)BATCH * 64;         // [B]

    unsigned short* x_bf = (unsigned short*)d_ws;                         // [B][64] bf16
    unsigned char*  blobG = (unsigned char*)(x_bf + (size_t)BATCH * 64);  // 63 * 21504 B

    // grid: 1024 x-convert | 63 blob | 64 d0-spline blocks
    prep_kernel<<<1024 + LAYERS + 64, 256, 0, stream>>>(
        x, ip, W1, W2, W3, b1, b2, b3, x_bf, blobG, z, ld);
    mlp_rqs_kernel<<<dim3(BATCH / BM, LAYERS), 256, 0, stream>>>(
        x, x_bf, blobG, z, ld);
}